// Round 10
// baseline (355.449 us; speedup 1.0000x reference)
//
#include <hip/hip_runtime.h>
#include <hip/hip_bf16.h>
#include <stdint.h>

// Problem constants
#define BB 2
#define NN 2048
#define DD 512
#define HH 8
#define DHH 64
// bh count = 16, per-head Q/K/V = 2048*64 elems = 131072

typedef __attribute__((ext_vector_type(8))) short bf16x8;   // 8 bf16 = 4 VGPR
typedef __attribute__((ext_vector_type(4))) float f32x4;    // MFMA C/D frag

#define LOG2E 1.44269504088896340736f

#if __has_builtin(__builtin_amdgcn_exp2f)
#define QSCALE (0.125f * LOG2E)
#define EXP2(x) __builtin_amdgcn_exp2f(x)
#else
#define QSCALE 0.125f
#define EXP2(x) __expf(x)
#endif

static __device__ __forceinline__ unsigned short f2bf(float f) {
    union { float f; unsigned u; } v; v.f = f;
    unsigned r = v.u + 0x7fffu + ((v.u >> 16) & 1u);  // RNE
    return (unsigned short)(r >> 16);
}

// pack two floats -> bf16 pair, COMPILER-VISIBLE (emits v_cvt_pk_bf16_f32)
static __device__ __forceinline__ unsigned pk2(float a, float b) {
    __hip_bfloat162 h = __float22bfloat162_rn(make_float2(a, b));
    union { __hip_bfloat162 h; unsigned u; } cv; cv.h = h;
    return cv.u;
}

static __device__ __forceinline__ bf16x8 ld8(const unsigned short* p) {
    bf16x8 v; __builtin_memcpy(&v, p, 16); return v;
}

// async global->LDS, 16B per lane; LDS dest = wave-uniform base + lane*16
static __device__ __forceinline__ void gld_lds16(const void* g, void* l) {
    __builtin_amdgcn_global_load_lds((const __attribute__((address_space(1))) void*)g,
                                     (__attribute__((address_space(3))) void*)l, 16, 0, 0);
}

// Manual grid barrier v2. R7's protocol passed correctness; its cost was the
// POLL RATE: s_sleep(1)=64cy * ~1000 blocks = fabric-hammering that throttled
// producers. s_sleep(64)=4096cy cuts poll traffic 64x (<=1.7us added latency).
// Check-before-sleep: last arriver never sleeps. Safe iff grid exactly co-resident.
static __device__ __forceinline__ void grid_barrier(unsigned* cnt, unsigned n) {
    __syncthreads();    // compiler drains vmcnt/lgkmcnt before s_barrier -> stores in L2
    if (threadIdx.x == 0) {
        __threadfence();
        atomicAdd(cnt, 1u);
        while (__hip_atomic_load(cnt, __ATOMIC_RELAXED, __HIP_MEMORY_SCOPE_AGENT) < n) {
            __builtin_amdgcn_s_sleep(64);
        }
        __threadfence();
    }
    __syncthreads();
}

// =============== K1: prep (grid-stride) -> grid barrier -> QKV proj GEMM ===============
// grid 768 = 3 blocks/CU exactly (48KB LDS, launch_bounds(256,3)) -> co-residency holds.
__global__ __launch_bounds__(256, 3)
void ca_k1(const float* __restrict__ x,
           const float* __restrict__ w0, const float* __restrict__ w1,
           const float* __restrict__ w2, const float* __restrict__ w3,
           unsigned short* __restrict__ xb, unsigned short* __restrict__ wts,
           unsigned short* __restrict__ qkv, unsigned short* __restrict__ vt,
           unsigned* __restrict__ bar) {
    __shared__ __align__(16) char sm[49152];
    int tid = threadIdx.x;

    // ---------------- phase A: prep ----------------
    {
        float (*T)[65] = (float (*)[65])sm;
        for (int u = blockIdx.x; u < 2304; u += 768) {
            if (u < 2048) {
                int gid = u * 256 + tid;
                float4 v = ((const float4*)x)[gid];
                ushort4 o;
                o.x = f2bf(v.x); o.y = f2bf(v.y); o.z = f2bf(v.z); o.w = f2bf(v.w);
                ((ushort4*)xb)[gid] = o;
            } else {
                int bb = u - 2048;
                int z = bb >> 6, t = bb & 63;
                const float* W = (z == 0) ? w0 : (z == 1) ? w1 : (z == 2) ? w2 : w3;
                unsigned short* out = wts + z * 262144;
                int k0 = (t & 7) << 6, n0 = (t >> 3) << 6;
                int c = tid & 63, r4 = tid >> 6;
#pragma unroll
                for (int rr = 0; rr < 16; ++rr) {
                    int r = r4 * 16 + rr;
                    T[r][c] = W[(k0 + r) * 512 + n0 + c];
                }
                __syncthreads();
#pragma unroll
                for (int rr = 0; rr < 16; ++rr) {
                    int r = r4 * 16 + rr;
                    out[(n0 + r) * 512 + k0 + c] = f2bf(T[c][r]);
                }
            }
        }
    }
    grid_barrier(bar, 768);

    // ---------------- phase B: QKV projection GEMM (R5/R9 dbuf counted-vmcnt body) -----
    {
        char* AshB = sm;            // [2][128*64] bf16 = 32KB
        char* BshB = sm + 32768;    // [2][64*64]  bf16 = 16KB
        int px = blockIdx.x & 31, py = blockIdx.x >> 5;
        int z = py >> 3;
        const unsigned short* BT = wts + z * 262144;
        unsigned short* out = qkv + z * 2097152;
        int w = tid >> 6, lane = tid & 63;
        int c = lane & 15, qd = lane >> 4;
        int m0 = px * 128 + w * 16;          // wave covers m0 and m0+64
        int n0 = (py & 7) * 64;

        int lr = lane >> 3, ls = lane & 7;
        int soff = lr * 512 + ((ls ^ (lr & 7)) << 3);
        const unsigned short* Ab = xb + (px * 128) * 512 + soff;
        const unsigned short* Bb = BT + n0 * 512 + soff;

        // prologue: stage chunk 0 -> buf 0
#pragma unroll
        for (int L = 0; L < 4; ++L)
            gld_lds16(Ab + (w * 32 + L * 8) * 512, AshB + (w * 32 + L * 8) * 128);
#pragma unroll
        for (int L = 0; L < 2; ++L)
            gld_lds16(Bb + (w * 16 + L * 8) * 512, BshB + (w * 16 + L * 8) * 128);

        f32x4 acc[2][4];
#pragma unroll
        for (int mt = 0; mt < 2; ++mt)
#pragma unroll
            for (int nb = 0; nb < 4; ++nb) acc[mt][nb] = (f32x4){0.f, 0.f, 0.f, 0.f};

        int cs = c & 7;
#pragma unroll
        for (int k = 0; k < 8; ++k) {
            int b = k & 1;
            if (k < 7) {
                int k0 = (k + 1) * 64;
#pragma unroll
                for (int L = 0; L < 4; ++L)
                    gld_lds16(Ab + k0 + (w * 32 + L * 8) * 512,
                              AshB + (b ^ 1) * 16384 + (w * 32 + L * 8) * 128);
#pragma unroll
                for (int L = 0; L < 2; ++L)
                    gld_lds16(Bb + k0 + (w * 16 + L * 8) * 512,
                              BshB + (b ^ 1) * 8192 + (w * 16 + L * 8) * 128);
                asm volatile("s_waitcnt vmcnt(6)" ::: "memory");
            } else {
                asm volatile("s_waitcnt vmcnt(0)" ::: "memory");
            }
            __syncthreads();
            bf16x8 a[2][2], bq[4][2];
#pragma unroll
            for (int mt = 0; mt < 2; ++mt)
#pragma unroll
                for (int kk = 0; kk < 2; ++kk)
                    a[mt][kk] = ld8((const unsigned short*)(AshB + b * 16384 +
                                    (w * 16 + mt * 64 + c) * 128 + (((kk * 4 + qd) ^ cs) << 4)));
#pragma unroll
            for (int nb = 0; nb < 4; ++nb)
#pragma unroll
                for (int kk = 0; kk < 2; ++kk)
                    bq[nb][kk] = ld8((const unsigned short*)(BshB + b * 8192 +
                                     (nb * 16 + c) * 128 + (((kk * 4 + qd) ^ cs) << 4)));
            asm volatile("s_waitcnt lgkmcnt(0)" ::: "memory");
            __syncthreads();
#pragma unroll
            for (int kk = 0; kk < 2; ++kk)
#pragma unroll
                for (int nb = 0; nb < 4; ++nb) {
                    acc[0][nb] = __builtin_amdgcn_mfma_f32_16x16x32_bf16(a[0][kk], bq[nb][kk], acc[0][nb], 0, 0, 0);
                    acc[1][nb] = __builtin_amdgcn_mfma_f32_16x16x32_bf16(a[1][kk], bq[nb][kk], acc[1][nb], 0, 0, 0);
                }
        }

        if (z == 2) {
#pragma unroll
            for (int mt = 0; mt < 2; ++mt) {
                int ib = m0 + mt * 64 + qd * 4;
                int b = ib >> 11, i = ib & 2047;
#pragma unroll
                for (int nb = 0; nb < 4; ++nb) {
                    int col = n0 + nb * 16 + c;
                    int h = col >> 6, d = col & 63;
                    ushort4 pk;
                    pk.x = f2bf(acc[mt][nb][0]); pk.y = f2bf(acc[mt][nb][1]);
                    pk.z = f2bf(acc[mt][nb][2]); pk.w = f2bf(acc[mt][nb][3]);
                    *(ushort4*)(vt + (((b << 3) + h) * 64 + d) * 2048 + i) = pk;
                }
            }
        } else {
            float scale = (z == 0) ? QSCALE : 1.0f;
#pragma unroll
            for (int mt = 0; mt < 2; ++mt)
#pragma unroll
                for (int nb = 0; nb < 4; ++nb) {
#pragma unroll
                    for (int r = 0; r < 4; ++r) {
                        int row = m0 + mt * 64 + qd * 4 + r;
                        int col = n0 + nb * 16 + c;
                        int b = row >> 11, i = row & 2047, h = col >> 6, d = col & 63;
                        out[(((b << 3) + h) * 2048 + i) * 64 + d] = f2bf(acc[mt][nb][r] * scale);
                    }
                }
        }
    }
}

// =============== K2: flash attention (R9 body) -> grid barrier -> output GEMM ===========
// grid 1024 = 4 blocks/CU exactly (38.4KB LDS, launch_bounds(256,4)) -> co-resident.
__global__ __launch_bounds__(256, 4)
void ca_k2(const unsigned short* __restrict__ Q,
           const unsigned short* __restrict__ K,
           const unsigned short* __restrict__ VTp,
           const float* __restrict__ rel_pos,
           const float* __restrict__ c_emb,
           unsigned short* __restrict__ Ob,
           const unsigned short* __restrict__ WoT,
           const float* __restrict__ bias,
           float* __restrict__ out,
           unsigned* __restrict__ bar) {
    __shared__ __align__(16) char smem[37904];
    int tid = threadIdx.x;

    // ---------------- phase A: flash attention (R9: hoisted QK + setprio) -------------
    {
        unsigned (*Ptu)[16][16] = (unsigned (*)[16][16])(smem + 32768);
        float* red = (float*)smem;                       // [3][64][41] floats
        float2* lrg = (float2*)(smem + 36864);           // (rel*QSCALE, gate) x 129

        int bx = blockIdx.x;
        int xcd = bx & 7, slot = bx >> 3;
        int bh = xcd + ((slot >> 6) << 3);
        int it = slot & 63;
        int b = bh >> 3, h = bh & 7;
        int w = tid >> 6, lane = tid & 63;
        int c = lane & 15, qd = lane >> 4;
        int i0 = it * 32;

        if (tid < 129) {
            lrg[tid] = make_float2(rel_pos[tid * 8 + h] * QSCALE, c_emb[tid * 8 + h]);
        }

        const unsigned short* Qh = Q   + bh * 131072;
        const unsigned short* Kh = K   + bh * 131072;
        const unsigned short* Vh = VTp + bh * 131072;
        char* kw = smem + w * 4096;                 // wave-private K slab (32 rows x 128B)
        char* vw = smem + 16384 + w * 4096;         // wave-private V slab (64 rows x 64B)

        int koff[4], voff[4];
#pragma unroll
        for (int L = 0; L < 4; ++L) {
            int kr = L * 8 + (lane >> 3);
            koff[L] = kr * 64 + (((lane & 7) ^ ((kr >> 1) & 7)) << 3);
            int vr = L * 16 + (lane >> 2);
            voff[L] = vr * 2048 + (((lane & 3) ^ ((lane >> 3) & 3)) << 3);
        }

        {
            int j0 = w * 32;
#pragma unroll
            for (int L = 0; L < 4; ++L) gld_lds16(Kh + j0 * 64 + koff[L], kw + L * 1024);
#pragma unroll
            for (int L = 0; L < 4; ++L) gld_lds16(Vh + j0 + voff[L], vw + L * 1024);
        }

        bf16x8 aq[2][2];
#pragma unroll
        for (int qt = 0; qt < 2; ++qt) {
            aq[qt][0] = ld8(Qh + (i0 + qt * 16 + c) * 64 + qd * 8);
            aq[qt][1] = ld8(Qh + (i0 + qt * 16 + c) * 64 + 32 + qd * 8);
        }

        f32x4 o2[2][4];
        float lp2[2][4];
#pragma unroll
        for (int qt = 0; qt < 2; ++qt)
#pragma unroll
            for (int db = 0; db < 4; ++db) {
                o2[qt][db] = (f32x4){0.f, 0.f, 0.f, 0.f};
                lp2[qt][db] = 0.f;
            }

        __syncthreads();   // lrg ready

        int ksw = c & 7;
        int vsw = (c >> 1) & 3;

        for (int t = 0; t < 16; ++t) {
            asm volatile("s_waitcnt vmcnt(4)" ::: "memory");
            __builtin_amdgcn_sched_barrier(0);
            bf16x8 bk0a = ld8((const unsigned short*)(kw + (2 * c) * 128     + (((qd)     ^ ksw) << 4)));
            bf16x8 bk0b = ld8((const unsigned short*)(kw + (2 * c) * 128     + (((qd + 4) ^ ksw) << 4)));
            bf16x8 bk1a = ld8((const unsigned short*)(kw + (2 * c + 1) * 128 + (((qd)     ^ ksw) << 4)));
            bf16x8 bk1b = ld8((const unsigned short*)(kw + (2 * c + 1) * 128 + (((qd + 4) ^ ksw) << 4)));
            asm volatile("s_waitcnt vmcnt(0)" ::: "memory");
            __builtin_amdgcn_sched_barrier(0);
            bf16x8 bv[4];
#pragma unroll
            for (int db = 0; db < 4; ++db)
                bv[db] = ld8((const unsigned short*)(vw + (db * 16 + c) * 64 + ((qd ^ vsw) << 4)));
            asm volatile("s_waitcnt lgkmcnt(0)" ::: "memory");
            __builtin_amdgcn_sched_barrier(0);
            if (t < 15) {
                int j0n = ((t + 1) * 4 + w) * 32;
#pragma unroll
                for (int L = 0; L < 4; ++L) gld_lds16(Kh + j0n * 64 + koff[L], kw + L * 1024);
#pragma unroll
                for (int L = 0; L < 4; ++L) gld_lds16(Vh + j0n + voff[L], vw + L * 1024);
            }

            int j0 = (t * 4 + w) * 32;

            f32x4 s[2][2];
            __builtin_amdgcn_s_setprio(1);
#pragma unroll
            for (int qt = 0; qt < 2; ++qt) {
                s[qt][0] = (f32x4){0.f, 0.f, 0.f, 0.f};
                s[qt][1] = (f32x4){0.f, 0.f, 0.f, 0.f};
                s[qt][0] = __builtin_amdgcn_mfma_f32_16x16x32_bf16(aq[qt][0], bk0a, s[qt][0], 0, 0, 0);
                s[qt][1] = __builtin_amdgcn_mfma_f32_16x16x32_bf16(aq[qt][0], bk1a, s[qt][1], 0, 0, 0);
                s[qt][0] = __builtin_amdgcn_mfma_f32_16x16x32_bf16(aq[qt][1], bk0b, s[qt][0], 0, 0, 0);
                s[qt][1] = __builtin_amdgcn_mfma_f32_16x16x32_bf16(aq[qt][1], bk1b, s[qt][1], 0, 0, 0);
            }
            __builtin_amdgcn_s_setprio(0);

#pragma unroll
            for (int qt = 0; qt < 2; ++qt) {
                int iqt0 = i0 + qt * 16;
                int iq = iqt0 + qd * 4;
                bool lowc  = (j0 + 31 - iqt0) <= -64;
                bool highc = (j0 - (iqt0 + 15)) >= 64;
                if (lowc || highc) {
                    int d = lowc ? 0 : 128;
                    float2 gg = lrg[d];
#pragma unroll
                    for (int r = 0; r < 4; ++r) {
                        float t0 = EXP2(s[qt][0][r] + gg.x);
                        float t1 = EXP2(s[qt][1][r] + gg.x);
                        lp2[qt][r] += t0 + t1;
                        Ptu[w][qd * 4 + r][c] = pk2(t0 * gg.y, t1 * gg.y);
                    }
                } else {
#pragma unroll
                    for (int r = 0; r < 4; ++r) {
                        int i = iq + r;
                        int j = j0 + 2 * c;
                        int d0 = j - i;     d0 = (d0 < -64) ? -64 : (d0 > 64 ? 64 : d0); d0 += 64;
                        int d1 = j + 1 - i; d1 = (d1 < -64) ? -64 : (d1 > 64 ? 64 : d1); d1 += 64;
                        float2 g0 = lrg[d0];
                        float2 g1 = lrg[d1];
                        float t0 = EXP2(s[qt][0][r] + g0.x);
                        float t1 = EXP2(s[qt][1][r] + g1.x);
                        lp2[qt][r] += t0 + t1;
                        Ptu[w][qd * 4 + r][c] = pk2(t0 * g0.y, t1 * g1.y);
                    }
                }
                bf16x8 ap = ld8((const unsigned short*)&Ptu[w][c][0] + qd * 8);
                __builtin_amdgcn_s_setprio(1);
#pragma unroll
                for (int db = 0; db < 4; ++db)
                    o2[qt][db] = __builtin_amdgcn_mfma_f32_16x16x32_bf16(ap, bv[db], o2[qt][db], 0, 0, 0);
                __builtin_amdgcn_s_setprio(0);
            }
        }

        __syncthreads();
        if (w > 0) {
            float* dst = red + (w - 1) * (64 * 41) + lane * 41;
#pragma unroll
            for (int qt = 0; qt < 2; ++qt)
#pragma unroll
                for (int db = 0; db < 4; ++db)
#pragma unroll
                    for (int r = 0; r < 4; ++r)
                        dst[qt * 16 + db * 4 + r] = o2[qt][db][r];
#pragma unroll
            for (int qt = 0; qt < 2; ++qt)
#pragma unroll
                for (int r = 0; r < 4; ++r)
                    dst[32 + qt * 4 + r] = lp2[qt][r];
        }
        __syncthreads();
        if (w == 0) {
#pragma unroll
            for (int ww = 0; ww < 3; ++ww) {
                const float* src = red + ww * (64 * 41) + lane * 41;
#pragma unroll
                for (int qt = 0; qt < 2; ++qt) {
#pragma unroll
                    for (int db = 0; db < 4; ++db)
#pragma unroll
                        for (int r = 0; r < 4; ++r)
                            o2[qt][db][r] += src[qt * 16 + db * 4 + r];
#pragma unroll
                    for (int r = 0; r < 4; ++r)
                        lp2[qt][r] += src[32 + qt * 4 + r];
                }
            }
#pragma unroll
            for (int qt = 0; qt < 2; ++qt)
#pragma unroll
                for (int r = 0; r < 4; ++r) {
                    lp2[qt][r] += __shfl_xor(lp2[qt][r], 1);
                    lp2[qt][r] += __shfl_xor(lp2[qt][r], 2);
                    lp2[qt][r] += __shfl_xor(lp2[qt][r], 4);
                    lp2[qt][r] += __shfl_xor(lp2[qt][r], 8);
                }
#pragma unroll
            for (int qt = 0; qt < 2; ++qt)
#pragma unroll
                for (int db = 0; db < 4; ++db)
#pragma unroll
                    for (int r = 0; r < 4; ++r) {
                        int row = b * 2048 + i0 + qt * 16 + qd * 4 + r;
                        int col = h * 64 + db * 16 + c;
                        Ob[row * 512 + col] = f2bf(o2[qt][db][r] / lp2[qt][r]);
                    }
        }
    }

    grid_barrier(bar, 1024);

    // ---------------- phase B: output GEMM (blocks < 512, R5 dbuf body) ----------------
    if (blockIdx.x < 512) {
        char* AshB = smem;            // [2][64*64] bf16 = 16KB
        char* BshB = smem + 16384;    // [2][64*64] bf16 = 16KB
        int u = blockIdx.x;
        int px = u & 63, py = u >> 6;
        int w = tid >> 6, lane = tid & 63;
        int c = lane & 15, qd = lane >> 4;
        int m0 = px * 64 + w * 16;
        int n0 = py * 64;

        int lr = lane >> 3, ls = lane & 7;
        int soff = lr * 512 + ((ls ^ (lr & 7)) << 3);
        const unsigned short* Ab = Ob + (px * 64) * 512 + soff;
        const unsigned short* Bb = WoT + n0 * 512 + soff;

#pragma unroll
        for (int L = 0; L < 2; ++L) {
            gld_lds16(Ab + (w * 16 + L * 8) * 512, AshB + (w * 16 + L * 8) * 128);
            gld_lds16(Bb + (w * 16 + L * 8) * 512, BshB + (w * 16 + L * 8) * 128);
        }

        f32x4 acc[4];
#pragma unroll
        for (int nb = 0; nb < 4; ++nb) acc[nb] = (f32x4){0.f, 0.f, 0.f, 0.f};

        int cs = c & 7;
#pragma unroll
        for (int k = 0; k < 8; ++k) {
            int b = k & 1;
            if (k < 7) {
                int k0 = (k + 1) * 64;
#pragma unroll
                for (int L = 0; L < 2; ++L) {
                    gld_lds16(Ab + k0 + (w * 16 + L * 8) * 512,
                              AshB + (b ^ 1) * 8192 + (w * 16 + L * 8) * 128);
                    gld_lds16(Bb + k0 + (w * 16 + L * 8) * 512,
                              BshB + (b ^ 1) * 8192 + (w * 16 + L * 8) * 128);
                }
                asm volatile("s_waitcnt vmcnt(4)" ::: "memory");
            } else {
                asm volatile("s_waitcnt vmcnt(0)" ::: "memory");
            }
            __syncthreads();
            bf16x8 a[2], bq[4][2];
#pragma unroll
            for (int kk = 0; kk < 2; ++kk)
                a[kk] = ld8((const unsigned short*)(AshB + b * 8192 +
                            (w * 16 + c) * 128 + (((kk * 4 + qd) ^ cs) << 4)));
#pragma unroll
            for (int nb = 0; nb < 4; ++nb)
#pragma unroll
                for (int kk = 0; kk < 2; ++kk)
                    bq[nb][kk] = ld8((const unsigned short*)(BshB + b * 8192 +
                                     (nb * 16 + c) * 128 + (((kk * 4 + qd) ^ cs) << 4)));
            asm volatile("s_waitcnt lgkmcnt(0)" ::: "memory");
            __syncthreads();
#pragma unroll
            for (int kk = 0; kk < 2; ++kk)
#pragma unroll
                for (int nb = 0; nb < 4; ++nb)
                    acc[nb] = __builtin_amdgcn_mfma_f32_16x16x32_bf16(a[kk], bq[nb][kk], acc[nb], 0, 0, 0);
        }
#pragma unroll
        for (int nb = 0; nb < 4; ++nb) {
#pragma unroll
            for (int r = 0; r < 4; ++r) {
                int row = m0 + qd * 4 + r;
                int col = n0 + nb * 16 + c;
                out[row * 512 + col] = acc[nb][r] + bias[col];
            }
        }
    }
}

extern "C" void kernel_launch(void* const* d_in, const int* in_sizes, int n_in,
                              void* d_out, int out_size, void* d_ws, size_t ws_size,
                              hipStream_t stream) {
    const float* x   = (const float*)d_in[0];
    const float* Wq  = (const float*)d_in[1];
    const float* Wk  = (const float*)d_in[2];
    const float* Wv  = (const float*)d_in[3];
    const float* rel = (const float*)d_in[4];
    const float* cem = (const float*)d_in[5];
    const float* Wo  = (const float*)d_in[6];
    const float* bo  = (const float*)d_in[7];
    float* out = (float*)d_out;
    char* ws = (char*)d_ws;

    unsigned short* xb  = (unsigned short*)(ws);              // 4 MB
    unsigned short* wts = (unsigned short*)(ws + 4194304);    // 2 MB
    unsigned short* qkv = (unsigned short*)(ws + 6291456);    // 12 MB (q,k; v slot unused)
    unsigned short* vt  = (unsigned short*)(ws + 18874368);   // 4 MB  vT bf16 [bh][DH][N]
    unsigned short* ob  = (unsigned short*)(ws + 23068672);   // 4 MB
    unsigned* bars      = (unsigned*)(ws + 27262976);         // 2 barrier counters

    // zero barrier counters (in-graph, re-runs every replay)
    hipMemsetAsync(bars, 0, 8, stream);

    hipLaunchKernelGGL(ca_k1, dim3(768), dim3(256), 0, stream,
                       x, Wq, Wk, Wv, Wo, xb, wts, qkv, vt, bars);
    hipLaunchKernelGGL(ca_k2, dim3(1024), dim3(256), 0, stream,
                       qkv, qkv + 2097152, vt, rel, cem, ob,
                       wts + 3 * 262144, bo, out, bars + 1);
}

// Round 11
// 159.332 us; speedup vs baseline: 2.2309x; 2.2309x over previous
//
#include <hip/hip_runtime.h>
#include <hip/hip_bf16.h>
#include <stdint.h>

// Problem constants
#define BB 2
#define NN 2048
#define DD 512
#define HH 8
#define DHH 64
// bh count = 16, per-head Q/K/V = 2048*64 elems = 131072

typedef __attribute__((ext_vector_type(8))) short bf16x8;   // 8 bf16 = 4 VGPR
typedef __attribute__((ext_vector_type(4))) float f32x4;    // MFMA C/D frag

#define LOG2E 1.44269504088896340736f

#if __has_builtin(__builtin_amdgcn_exp2f)
#define QSCALE (0.125f * LOG2E)
#define EXP2(x) __builtin_amdgcn_exp2f(x)
#else
#define QSCALE 0.125f
#define EXP2(x) __expf(x)
#endif

static __device__ __forceinline__ unsigned short f2bf(float f) {
    union { float f; unsigned u; } v; v.f = f;
    unsigned r = v.u + 0x7fffu + ((v.u >> 16) & 1u);  // RNE
    return (unsigned short)(r >> 16);
}

// pack two floats -> bf16 pair, COMPILER-VISIBLE (emits v_cvt_pk_bf16_f32)
static __device__ __forceinline__ unsigned pk2(float a, float b) {
    __hip_bfloat162 h = __float22bfloat162_rn(make_float2(a, b));
    union { __hip_bfloat162 h; unsigned u; } cv; cv.h = h;
    return cv.u;
}

static __device__ __forceinline__ bf16x8 ld8(const unsigned short* p) {
    bf16x8 v; __builtin_memcpy(&v, p, 16); return v;
}

// async global->LDS, 16B per lane; LDS dest = wave-uniform base + lane*16
static __device__ __forceinline__ void gld_lds16(const void* g, void* l) {
    __builtin_amdgcn_global_load_lds((const __attribute__((address_space(1))) void*)g,
                                     (__attribute__((address_space(3))) void*)l, 16, 0, 0);
}

// ------------- QKV projection GEMM v4: SELF-STAGING from f32 (prep kernel deleted) ----
// grid (32, 24): by>>3 = z (0=Q,1=K,2=V), (by&7)*64 = n0.
// Each chunk (BK=64): A staged from f32 x (reg->cvt->swizzled ds_write_b128);
// B staged from f32 W with in-flight transpose (thread = one BT row x 16 k's,
// 16 stride-512 loads; W slab is L2-resident, shared by 32 px-blocks).
// Loads for chunk k+1 are issued AFTER the buf-ready barrier so the compiler's
// barrier waitcnt-drain doesn't serialize them; they fly during ds_read+MFMA.
// Read side + epilogue byte-identical to R9 (proven). Single LDS buffer (24KB).
__global__ __launch_bounds__(256, 3)
void ca_projf(const float* __restrict__ x,
              const float* __restrict__ w0, const float* __restrict__ w1,
              const float* __restrict__ w2,
              unsigned short* __restrict__ qkv,
              unsigned short* __restrict__ vt) {
    __shared__ __align__(16) unsigned short Ash[128 * 64];
    __shared__ __align__(16) unsigned short Bsh[64 * 64];
    int z = blockIdx.y >> 3;
    const float* W = (z == 0) ? w0 : (z == 1) ? w1 : w2;
    unsigned short* out = qkv + z * 2097152;
    int tid = threadIdx.x;
    int w = tid >> 6, lane = tid & 63;
    int c = lane & 15, qd = lane >> 4;
    int m0 = blockIdx.x * 128 + w * 16;          // wave covers m0 and m0+64
    int n0 = (blockIdx.y & 7) * 64;

    // A staging assignment: rowA = tid>>1 (0..127), half ha = tid&1 (k-cols ha*32..+31)
    int rowA = tid >> 1, ha = tid & 1;
    const float* xA = x + (blockIdx.x * 128 + rowA) * 512 + ha * 32;
    // B staging assignment: nB = tid>>2 (0..63), kq = tid&3 (k-cols kq*16..+15)
    int nB = tid >> 2, kq = tid & 3;
    const float* wB = W + n0 + nB;               // + (k0+kq*16+j)*512

    float4 fA4[8];
    float  fB[16];
    // issue loads for chunk 0
#pragma unroll
    for (int j = 0; j < 8; ++j) fA4[j] = *(const float4*)(xA + j * 4);
#pragma unroll
    for (int j = 0; j < 16; ++j) fB[j] = wB[(kq * 16 + j) * 512];

    f32x4 acc[2][4];
#pragma unroll
    for (int mt = 0; mt < 2; ++mt)
#pragma unroll
        for (int nb = 0; nb < 4; ++nb) acc[mt][nb] = (f32x4){0.f, 0.f, 0.f, 0.f};

    int cs = c & 7;
    int ra7 = rowA & 7, nb7 = nB & 7;
    for (int k = 0; k < 8; ++k) {
        asm volatile("s_waitcnt vmcnt(0)" ::: "memory");   // chunk k loads arrived
        __syncthreads();                                   // buf free (reads of k-1 done)
        // cvt + swizzled write: A slots ha*4+q (q=0..3), phys = slot ^ (rowA&7)
#pragma unroll
        for (int q = 0; q < 4; ++q) {
            uint4 pkk;
            pkk.x = pk2(fA4[q * 2].x, fA4[q * 2].y);
            pkk.y = pk2(fA4[q * 2].z, fA4[q * 2].w);
            pkk.z = pk2(fA4[q * 2 + 1].x, fA4[q * 2 + 1].y);
            pkk.w = pk2(fA4[q * 2 + 1].z, fA4[q * 2 + 1].w);
            int sl = (ha * 4 + q) ^ ra7;
            *(uint4*)((char*)Ash + rowA * 128 + sl * 16) = pkk;
        }
        // B slots kq*2+q (q=0..1), phys = slot ^ (nB&7)
#pragma unroll
        for (int q = 0; q < 2; ++q) {
            uint4 pkk;
            pkk.x = pk2(fB[q * 8 + 0], fB[q * 8 + 1]);
            pkk.y = pk2(fB[q * 8 + 2], fB[q * 8 + 3]);
            pkk.z = pk2(fB[q * 8 + 4], fB[q * 8 + 5]);
            pkk.w = pk2(fB[q * 8 + 6], fB[q * 8 + 7]);
            int sl = (kq * 2 + q) ^ nb7;
            *(uint4*)((char*)Bsh + nB * 128 + sl * 16) = pkk;
        }
        __syncthreads();                                   // buf ready (writes drained)
        // issue loads for chunk k+1 AFTER the barrier (not drained by it)
        if (k < 7) {
            int k0n = (k + 1) * 64;
#pragma unroll
            for (int j = 0; j < 8; ++j) fA4[j] = *(const float4*)(xA + k0n + j * 4);
#pragma unroll
            for (int j = 0; j < 16; ++j) fB[j] = wB[(k0n + kq * 16 + j) * 512];
        }
        // frag reads + MFMA (identical to R9 read side, single buffer)
        bf16x8 a[2][2], bq[4][2];
#pragma unroll
        for (int mt = 0; mt < 2; ++mt)
#pragma unroll
            for (int kk = 0; kk < 2; ++kk)
                a[mt][kk] = ld8((const unsigned short*)((char*)Ash +
                                (w * 16 + mt * 64 + c) * 128 + (((kk * 4 + qd) ^ cs) << 4)));
#pragma unroll
        for (int nb = 0; nb < 4; ++nb)
#pragma unroll
            for (int kk = 0; kk < 2; ++kk)
                bq[nb][kk] = ld8((const unsigned short*)((char*)Bsh +
                                (nb * 16 + c) * 128 + (((kk * 4 + qd) ^ cs) << 4)));
#pragma unroll
        for (int kk = 0; kk < 2; ++kk)
#pragma unroll
            for (int nb = 0; nb < 4; ++nb) {
                acc[0][nb] = __builtin_amdgcn_mfma_f32_16x16x32_bf16(a[0][kk], bq[nb][kk], acc[0][nb], 0, 0, 0);
                acc[1][nb] = __builtin_amdgcn_mfma_f32_16x16x32_bf16(a[1][kk], bq[nb][kk], acc[1][nb], 0, 0, 0);
            }
    }

    if (z == 2) {
        // V: write transposed [bh][d][i], 4 consecutive i packed per store
#pragma unroll
        for (int mt = 0; mt < 2; ++mt) {
            int ib = m0 + mt * 64 + qd * 4;      // i base (4-aligned)
            int b = ib >> 11, i = ib & 2047;
#pragma unroll
            for (int nb = 0; nb < 4; ++nb) {
                int col = n0 + nb * 16 + c;      // h*64 + d
                int h = col >> 6, d = col & 63;
                ushort4 pk;
                pk.x = f2bf(acc[mt][nb][0]); pk.y = f2bf(acc[mt][nb][1]);
                pk.z = f2bf(acc[mt][nb][2]); pk.w = f2bf(acc[mt][nb][3]);
                *(ushort4*)(vt + (((b << 3) + h) * 64 + d) * 2048 + i) = pk;
            }
        }
    } else {
        float scale = (z == 0) ? QSCALE : 1.0f;
#pragma unroll
        for (int mt = 0; mt < 2; ++mt)
#pragma unroll
            for (int nb = 0; nb < 4; ++nb) {
#pragma unroll
                for (int r = 0; r < 4; ++r) {
                    int row = m0 + mt * 64 + qd * 4 + r;
                    int col = n0 + nb * 16 + c;
                    int b = row >> 11, i = row & 2047, h = col >> 6, d = col & 63;
                    out[(((b << 3) + h) * 2048 + i) * 64 + d] = f2bf(acc[mt][nb][r] * scale);
                }
            }
    }
}

// ------------- Flash attention v10 + Wo-prep rider blocks -------------
// grid 1088: blocks 0..63 transpose-cast Wo -> woT (needed only by ca_gemm_out,
// which launches after; no intra-kernel ordering dependence). Blocks 64..1087
// run the R9-proven flash body (hoisted QK + setprio + split vmcnt).
__global__ __launch_bounds__(256, 4)
void ca_flash(const unsigned short* __restrict__ Q,
              const unsigned short* __restrict__ K,
              const unsigned short* __restrict__ VT,
              const float* __restrict__ rel_pos,
              const float* __restrict__ c_emb,
              unsigned short* __restrict__ Ob,
              const float* __restrict__ Wo,
              unsigned short* __restrict__ woT) {
    __shared__ __align__(16) char smem[37904];

    if (blockIdx.x < 64) {
        // ---- Wo transpose-cast rider (prep's weight body) ----
        float (*T)[65] = (float (*)[65])smem;     // 16.6KB < 37.9KB
        int t = blockIdx.x;
        int k0 = (t & 7) << 6, n0 = (t >> 3) << 6;
        int c = threadIdx.x & 63, r4 = threadIdx.x >> 6;
#pragma unroll
        for (int rr = 0; rr < 16; ++rr) {
            int r = r4 * 16 + rr;
            T[r][c] = Wo[(k0 + r) * 512 + n0 + c];
        }
        __syncthreads();
#pragma unroll
        for (int rr = 0; rr < 16; ++rr) {
            int r = r4 * 16 + rr;
            woT[(n0 + r) * 512 + k0 + c] = f2bf(T[c][r]);
        }
        return;
    }

    unsigned (*Ptu)[16][16] = (unsigned (*)[16][16])(smem + 32768);
    float* red = (float*)smem;                       // [3][64][41] floats
    float2* lrg = (float2*)(smem + 36864);           // (rel*QSCALE, gate) x 129

    int bx = blockIdx.x - 64;
    int xcd = bx & 7, slot = bx >> 3;           // slot 0..127
    int bh = xcd + ((slot >> 6) << 3);          // heads {xcd, xcd+8} per XCD
    int it = slot & 63;
    int b = bh >> 3, h = bh & 7;
    int w = threadIdx.x >> 6, lane = threadIdx.x & 63;
    int c = lane & 15, qd = lane >> 4;
    int i0 = it * 32;

    if (threadIdx.x < 129) {
        lrg[threadIdx.x] = make_float2(rel_pos[threadIdx.x * 8 + h] * QSCALE,
                                       c_emb[threadIdx.x * 8 + h]);
    }

    const unsigned short* Qh = Q  + bh * 131072;
    const unsigned short* Kh = K  + bh * 131072;
    const unsigned short* Vh = VT + bh * 131072;
    char* kw = smem + w * 4096;                 // wave-private K slab (32 rows x 128B)
    char* vw = smem + 16384 + w * 4096;         // wave-private V slab (64 rows x 64B)

    int koff[4], voff[4];
#pragma unroll
    for (int L = 0; L < 4; ++L) {
        int kr = L * 8 + (lane >> 3);
        koff[L] = kr * 64 + (((lane & 7) ^ ((kr >> 1) & 7)) << 3);
        int vr = L * 16 + (lane >> 2);
        voff[L] = vr * 2048 + (((lane & 3) ^ ((lane >> 3) & 3)) << 3);
    }

    // prologue: stage tile t=0 (j0 = w*32): K first, then V (vmcnt(4) split)
    {
        int j0 = w * 32;
#pragma unroll
        for (int L = 0; L < 4; ++L) gld_lds16(Kh + j0 * 64 + koff[L], kw + L * 1024);
#pragma unroll
        for (int L = 0; L < 4; ++L) gld_lds16(Vh + j0 + voff[L], vw + L * 1024);
    }

    bf16x8 aq[2][2];
#pragma unroll
    for (int qt = 0; qt < 2; ++qt) {
        aq[qt][0] = ld8(Qh + (i0 + qt * 16 + c) * 64 + qd * 8);
        aq[qt][1] = ld8(Qh + (i0 + qt * 16 + c) * 64 + 32 + qd * 8);
    }

    f32x4 o2[2][4];
    float lp2[2][4];
#pragma unroll
    for (int qt = 0; qt < 2; ++qt)
#pragma unroll
        for (int db = 0; db < 4; ++db) {
            o2[qt][db] = (f32x4){0.f, 0.f, 0.f, 0.f};
            lp2[qt][db] = 0.f;
        }

    __syncthreads();   // lrg ready (also drains prologue stage - harmless)

    int ksw  = c & 7;          // (row>>1)&7 for K rows 2c, 2c+1
    int vsw  = (c >> 1) & 3;   // (row>>1)&3 for V rows db*16+c

    for (int t = 0; t < 16; ++t) {
        asm volatile("s_waitcnt vmcnt(4)" ::: "memory");
        __builtin_amdgcn_sched_barrier(0);
        bf16x8 bk0a = ld8((const unsigned short*)(kw + (2 * c) * 128     + (((qd)     ^ ksw) << 4)));
        bf16x8 bk0b = ld8((const unsigned short*)(kw + (2 * c) * 128     + (((qd + 4) ^ ksw) << 4)));
        bf16x8 bk1a = ld8((const unsigned short*)(kw + (2 * c + 1) * 128 + (((qd)     ^ ksw) << 4)));
        bf16x8 bk1b = ld8((const unsigned short*)(kw + (2 * c + 1) * 128 + (((qd + 4) ^ ksw) << 4)));
        asm volatile("s_waitcnt vmcnt(0)" ::: "memory");
        __builtin_amdgcn_sched_barrier(0);
        bf16x8 bv[4];
#pragma unroll
        for (int db = 0; db < 4; ++db)
            bv[db] = ld8((const unsigned short*)(vw + (db * 16 + c) * 64 + ((qd ^ vsw) << 4)));
        asm volatile("s_waitcnt lgkmcnt(0)" ::: "memory");
        __builtin_amdgcn_sched_barrier(0);
        if (t < 15) {
            int j0n = ((t + 1) * 4 + w) * 32;
#pragma unroll
            for (int L = 0; L < 4; ++L) gld_lds16(Kh + j0n * 64 + koff[L], kw + L * 1024);
#pragma unroll
            for (int L = 0; L < 4; ++L) gld_lds16(Vh + j0n + voff[L], vw + L * 1024);
        }

        int j0 = (t * 4 + w) * 32;

        // ---- hoisted QK: all 4 accumulators before any softmax ----
        f32x4 s[2][2];
        __builtin_amdgcn_s_setprio(1);
#pragma unroll
        for (int qt = 0; qt < 2; ++qt) {
            s[qt][0] = (f32x4){0.f, 0.f, 0.f, 0.f};
            s[qt][1] = (f32x4){0.f, 0.f, 0.f, 0.f};
            s[qt][0] = __builtin_amdgcn_mfma_f32_16x16x32_bf16(aq[qt][0], bk0a, s[qt][0], 0, 0, 0);
            s[qt][1] = __builtin_amdgcn_mfma_f32_16x16x32_bf16(aq[qt][0], bk1a, s[qt][1], 0, 0, 0);
            s[qt][0] = __builtin_amdgcn_mfma_f32_16x16x32_bf16(aq[qt][1], bk0b, s[qt][0], 0, 0, 0);
            s[qt][1] = __builtin_amdgcn_mfma_f32_16x16x32_bf16(aq[qt][1], bk1b, s[qt][1], 0, 0, 0);
        }
        __builtin_amdgcn_s_setprio(0);

#pragma unroll
        for (int qt = 0; qt < 2; ++qt) {
            int iqt0 = i0 + qt * 16;
            int iq = iqt0 + qd * 4;
            bool lowc  = (j0 + 31 - iqt0) <= -64;   // whole tile clamps to d=0
            bool highc = (j0 - (iqt0 + 15)) >= 64;  // whole tile clamps to d=128
            if (lowc || highc) {
                int d = lowc ? 0 : 128;
                float2 gg = lrg[d];                 // wave-uniform broadcast
#pragma unroll
                for (int r = 0; r < 4; ++r) {
                    float t0 = EXP2(s[qt][0][r] + gg.x);
                    float t1 = EXP2(s[qt][1][r] + gg.x);
                    lp2[qt][r] += t0 + t1;
                    Ptu[w][qd * 4 + r][c] = pk2(t0 * gg.y, t1 * gg.y);
                }
            } else {
#pragma unroll
                for (int r = 0; r < 4; ++r) {
                    int i = iq + r;
                    int j = j0 + 2 * c;
                    int d0 = j - i;     d0 = (d0 < -64) ? -64 : (d0 > 64 ? 64 : d0); d0 += 64;
                    int d1 = j + 1 - i; d1 = (d1 < -64) ? -64 : (d1 > 64 ? 64 : d1); d1 += 64;
                    float2 g0 = lrg[d0];
                    float2 g1 = lrg[d1];
                    float t0 = EXP2(s[qt][0][r] + g0.x);
                    float t1 = EXP2(s[qt][1][r] + g1.x);
                    lp2[qt][r] += t0 + t1;
                    Ptu[w][qd * 4 + r][c] = pk2(t0 * g0.y, t1 * g1.y);
                }
            }
            // same-wave RAW on Ptu: lgkmcnt ordering, no barrier needed
            bf16x8 ap = ld8((const unsigned short*)&Ptu[w][c][0] + qd * 8);
            __builtin_amdgcn_s_setprio(1);
#pragma unroll
            for (int db = 0; db < 4; ++db)
                o2[qt][db] = __builtin_amdgcn_mfma_f32_16x16x32_bf16(ap, bv[db], o2[qt][db], 0, 0, 0);
            __builtin_amdgcn_s_setprio(0);
        }
    }

    // ---- cross-wave combine (red overlaps staging slabs: barrier before reuse;
    //      last iter issued no prefetch, so no async LDS writes are in flight) ----
    __syncthreads();
    if (w > 0) {
        float* dst = red + (w - 1) * (64 * 41) + lane * 41;
#pragma unroll
        for (int qt = 0; qt < 2; ++qt)
#pragma unroll
            for (int db = 0; db < 4; ++db)
#pragma unroll
                for (int r = 0; r < 4; ++r)
                    dst[qt * 16 + db * 4 + r] = o2[qt][db][r];
#pragma unroll
        for (int qt = 0; qt < 2; ++qt)
#pragma unroll
            for (int r = 0; r < 4; ++r)
                dst[32 + qt * 4 + r] = lp2[qt][r];
    }
    __syncthreads();
    if (w == 0) {
#pragma unroll
        for (int ww = 0; ww < 3; ++ww) {
            const float* src = red + ww * (64 * 41) + lane * 41;
#pragma unroll
            for (int qt = 0; qt < 2; ++qt) {
#pragma unroll
                for (int db = 0; db < 4; ++db)
#pragma unroll
                    for (int r = 0; r < 4; ++r)
                        o2[qt][db][r] += src[qt * 16 + db * 4 + r];
#pragma unroll
                for (int r = 0; r < 4; ++r)
                    lp2[qt][r] += src[32 + qt * 4 + r];
            }
        }
#pragma unroll
        for (int qt = 0; qt < 2; ++qt)
#pragma unroll
            for (int r = 0; r < 4; ++r) {
                lp2[qt][r] += __shfl_xor(lp2[qt][r], 1);
                lp2[qt][r] += __shfl_xor(lp2[qt][r], 2);
                lp2[qt][r] += __shfl_xor(lp2[qt][r], 4);
                lp2[qt][r] += __shfl_xor(lp2[qt][r], 8);
            }
#pragma unroll
        for (int qt = 0; qt < 2; ++qt)
#pragma unroll
            for (int db = 0; db < 4; ++db)
#pragma unroll
                for (int r = 0; r < 4; ++r) {
                    int row = b * 2048 + i0 + qt * 16 + qd * 4 + r;
                    int col = h * 64 + db * 16 + c;
                    Ob[row * 512 + col] = f2bf(o2[qt][db][r] / lp2[qt][r]);
                }
    }
}

// ------------- Output GEMM v3: double-buffered staging, counted vmcnt, grid (64,8) ---
__global__ __launch_bounds__(256, 4)
void ca_gemm_out(const unsigned short* __restrict__ A,
                 const unsigned short* __restrict__ BT,
                 const float* __restrict__ bias,
                 float* __restrict__ out) {
    __shared__ __align__(16) unsigned short Ash[2][64 * 64];
    __shared__ __align__(16) unsigned short Bsh[2][64 * 64];
    int w = threadIdx.x >> 6, lane = threadIdx.x & 63;
    int c = lane & 15, qd = lane >> 4;
    int m0 = blockIdx.x * 64 + w * 16;
    int n0 = blockIdx.y * 64;

    int lr = lane >> 3, ls = lane & 7;
    int soff = lr * 512 + ((ls ^ (lr & 7)) << 3);
    const unsigned short* Ab = A + (blockIdx.x * 64) * 512 + soff;
    const unsigned short* Bb = BT + n0 * 512 + soff;

#pragma unroll
    for (int L = 0; L < 2; ++L) {
        gld_lds16(Ab + (w * 16 + L * 8) * 512, (char*)Ash[0] + (w * 16 + L * 8) * 128);
        gld_lds16(Bb + (w * 16 + L * 8) * 512, (char*)Bsh[0] + (w * 16 + L * 8) * 128);
    }

    f32x4 acc[4];
#pragma unroll
    for (int nb = 0; nb < 4; ++nb) acc[nb] = (f32x4){0.f, 0.f, 0.f, 0.f};

    int cs = c & 7;
#pragma unroll
    for (int k = 0; k < 8; ++k) {
        int b = k & 1;
        if (k < 7) {
            int k0 = (k + 1) * 64;
#pragma unroll
            for (int L = 0; L < 2; ++L) {
                gld_lds16(Ab + k0 + (w * 16 + L * 8) * 512, (char*)Ash[b ^ 1] + (w * 16 + L * 8) * 128);
                gld_lds16(Bb + k0 + (w * 16 + L * 8) * 512, (char*)Bsh[b ^ 1] + (w * 16 + L * 8) * 128);
            }
            asm volatile("s_waitcnt vmcnt(4)" ::: "memory");
        } else {
            asm volatile("s_waitcnt vmcnt(0)" ::: "memory");
        }
        __syncthreads();
        bf16x8 a[2], bq[4][2];
#pragma unroll
        for (int kk = 0; kk < 2; ++kk)
            a[kk] = ld8((const unsigned short*)((char*)Ash[b] +
                        (w * 16 + c) * 128 + (((kk * 4 + qd) ^ cs) << 4)));
#pragma unroll
        for (int nb = 0; nb < 4; ++nb)
#pragma unroll
            for (int kk = 0; kk < 2; ++kk)
                bq[nb][kk] = ld8((const unsigned short*)((char*)Bsh[b] +
                                (nb * 16 + c) * 128 + (((kk * 4 + qd) ^ cs) << 4)));
        asm volatile("s_waitcnt lgkmcnt(0)" ::: "memory");
        __syncthreads();
#pragma unroll
        for (int kk = 0; kk < 2; ++kk)
#pragma unroll
            for (int nb = 0; nb < 4; ++nb)
                acc[nb] = __builtin_amdgcn_mfma_f32_16x16x32_bf16(a[kk], bq[nb][kk], acc[nb], 0, 0, 0);
    }
#pragma unroll
    for (int nb = 0; nb < 4; ++nb) {
#pragma unroll
        for (int r = 0; r < 4; ++r) {
            int row = m0 + qd * 4 + r;
            int col = n0 + nb * 16 + c;
            out[row * 512 + col] = acc[nb][r] + bias[col];
        }
    }
}

extern "C" void kernel_launch(void* const* d_in, const int* in_sizes, int n_in,
                              void* d_out, int out_size, void* d_ws, size_t ws_size,
                              hipStream_t stream) {
    const float* x   = (const float*)d_in[0];
    const float* Wq  = (const float*)d_in[1];
    const float* Wk  = (const float*)d_in[2];
    const float* Wv  = (const float*)d_in[3];
    const float* rel = (const float*)d_in[4];
    const float* cem = (const float*)d_in[5];
    const float* Wo  = (const float*)d_in[6];
    const float* bo  = (const float*)d_in[7];
    float* out = (float*)d_out;
    char* ws = (char*)d_ws;

    unsigned short* woT = (unsigned short*)(ws + 4194304);    // 512 KB  Wo^T bf16
    unsigned short* qkv = (unsigned short*)(ws + 6291456);    // q,k (v slot unused)
    unsigned short* vt  = (unsigned short*)(ws + 18874368);   // 4 MB  vT bf16 [bh][DH][N]
    unsigned short* ob  = (unsigned short*)(ws + 23068672);   // 4 MB

    hipLaunchKernelGGL(ca_projf, dim3(32, 24), dim3(256), 0, stream, x, Wq, Wk, Wv, qkv, vt);
    hipLaunchKernelGGL(ca_flash, dim3(1088), dim3(256), 0, stream,
                       qkv, qkv + 2097152, vt, rel, cem, ob, Wo, woT);
    hipLaunchKernelGGL(ca_gemm_out, dim3(64, 8), dim3(256), 0, stream, ob, woT, bo, out);
}

// Round 12
// 134.371 us; speedup vs baseline: 2.6453x; 1.1858x over previous
//
#include <hip/hip_runtime.h>
#include <hip/hip_bf16.h>
#include <stdint.h>

// Problem constants
#define BB 2
#define NN 2048
#define DD 512
#define HH 8
#define DHH 64
// bh count = 16, per-head Q/K/V = 2048*64 elems = 131072

typedef __attribute__((ext_vector_type(8))) short bf16x8;   // 8 bf16 = 4 VGPR
typedef __attribute__((ext_vector_type(4))) float f32x4;    // MFMA C/D frag

#define LOG2E 1.44269504088896340736f

#if __has_builtin(__builtin_amdgcn_exp2f)
#define QSCALE (0.125f * LOG2E)
#define EXP2(x) __builtin_amdgcn_exp2f(x)
#else
#define QSCALE 0.125f
#define EXP2(x) __expf(x)
#endif

static __device__ __forceinline__ unsigned short f2bf(float f) {
    union { float f; unsigned u; } v; v.f = f;
    unsigned r = v.u + 0x7fffu + ((v.u >> 16) & 1u);  // RNE
    return (unsigned short)(r >> 16);
}

// pack two floats -> bf16 pair, COMPILER-VISIBLE (emits v_cvt_pk_bf16_f32)
static __device__ __forceinline__ unsigned pk2(float a, float b) {
    __hip_bfloat162 h = __float22bfloat162_rn(make_float2(a, b));
    union { __hip_bfloat162 h; unsigned u; } cv; cv.h = h;
    return cv.u;
}

static __device__ __forceinline__ bf16x8 ld8(const unsigned short* p) {
    bf16x8 v; __builtin_memcpy(&v, p, 16); return v;
}

// async global->LDS, 16B per lane; LDS dest = wave-uniform base + lane*16
static __device__ __forceinline__ void gld_lds16(const void* g, void* l) {
    __builtin_amdgcn_global_load_lds((const __attribute__((address_space(1))) void*)g,
                                     (__attribute__((address_space(3))) void*)l, 16, 0, 0);
}

// ---------------- prep: cast x -> bf16 (2 float4/thread), transpose Wq/Wk/Wv --------
// grid 1216: bx<1024 x-cast (2 float4 each); bx>=1024: 192 weight-transpose blocks.
// (Wo transpose rides on ca_flash blocks 0..63 — R11-verified, flash time unchanged.)
__global__ void ca_prep(const float* __restrict__ x,
                        const float* __restrict__ w0, const float* __restrict__ w1,
                        const float* __restrict__ w2,
                        unsigned short* __restrict__ xb, unsigned short* __restrict__ wts) {
    __shared__ float T[64][65];
    int bx = blockIdx.x;
    if (bx < 1024) {
        int gid = bx * 512 + threadIdx.x;
#pragma unroll
        for (int j = 0; j < 2; ++j) {
            float4 v = ((const float4*)x)[gid + j * 256];
            ushort4 o;
            o.x = f2bf(v.x); o.y = f2bf(v.y); o.z = f2bf(v.z); o.w = f2bf(v.w);
            ((ushort4*)xb)[gid + j * 256] = o;
        }
        return;
    }
    int bb = bx - 1024;
    int z = bb >> 6, t = bb & 63;
    const float* W = (z == 0) ? w0 : (z == 1) ? w1 : w2;
    unsigned short* out = wts + z * 262144;
    int k0 = (t & 7) << 6, n0 = (t >> 3) << 6;
    int c = threadIdx.x & 63, r4 = threadIdx.x >> 6;
#pragma unroll
    for (int rr = 0; rr < 16; ++rr) {
        int r = r4 * 16 + rr;
        T[r][c] = W[(k0 + r) * 512 + n0 + c];
    }
    __syncthreads();
#pragma unroll
    for (int rr = 0; rr < 16; ++rr) {
        int r = r4 * 16 + rr;
        out[(n0 + r) * 512 + k0 + c] = f2bf(T[c][r]);
    }
}

// ------------- QKV projection GEMM v3 (R9-proven): dbuf staging, counted vmcnt ------
__global__ __launch_bounds__(256, 3)
void ca_gemm_proj(const unsigned short* __restrict__ A,
                  const unsigned short* __restrict__ wts,
                  unsigned short* __restrict__ qkv,
                  unsigned short* __restrict__ vt) {
    __shared__ __align__(16) unsigned short Ash[2][128 * 64];
    __shared__ __align__(16) unsigned short Bsh[2][64 * 64];
    int z = blockIdx.y >> 3;
    const unsigned short* BT = wts + z * 262144;
    unsigned short* out = qkv + z * 2097152;
    int w = threadIdx.x >> 6, lane = threadIdx.x & 63;
    int c = lane & 15, qd = lane >> 4;
    int m0 = blockIdx.x * 128 + w * 16;          // wave covers m0 and m0+64
    int n0 = (blockIdx.y & 7) * 64;

    int lr = lane >> 3, ls = lane & 7;
    int soff = lr * 512 + ((ls ^ (lr & 7)) << 3);
    const unsigned short* Ab = A + (blockIdx.x * 128) * 512 + soff;
    const unsigned short* Bb = BT + n0 * 512 + soff;

    // prologue: stage chunk 0 -> buf 0
#pragma unroll
    for (int L = 0; L < 4; ++L)
        gld_lds16(Ab + (w * 32 + L * 8) * 512, (char*)Ash[0] + (w * 32 + L * 8) * 128);
#pragma unroll
    for (int L = 0; L < 2; ++L)
        gld_lds16(Bb + (w * 16 + L * 8) * 512, (char*)Bsh[0] + (w * 16 + L * 8) * 128);

    f32x4 acc[2][4];
#pragma unroll
    for (int mt = 0; mt < 2; ++mt)
#pragma unroll
        for (int nb = 0; nb < 4; ++nb) acc[mt][nb] = (f32x4){0.f, 0.f, 0.f, 0.f};

    int cs = c & 7;
#pragma unroll
    for (int k = 0; k < 8; ++k) {
        int b = k & 1;
        if (k < 7) {
            int k0 = (k + 1) * 64;
#pragma unroll
            for (int L = 0; L < 4; ++L)
                gld_lds16(Ab + k0 + (w * 32 + L * 8) * 512, (char*)Ash[b ^ 1] + (w * 32 + L * 8) * 128);
#pragma unroll
            for (int L = 0; L < 2; ++L)
                gld_lds16(Bb + k0 + (w * 16 + L * 8) * 512, (char*)Bsh[b ^ 1] + (w * 16 + L * 8) * 128);
            asm volatile("s_waitcnt vmcnt(6)" ::: "memory");   // chunk k done, k+1 in flight
        } else {
            asm volatile("s_waitcnt vmcnt(0)" ::: "memory");
        }
        __syncthreads();
        bf16x8 a[2][2], bq[4][2];
#pragma unroll
        for (int mt = 0; mt < 2; ++mt)
#pragma unroll
            for (int kk = 0; kk < 2; ++kk)
                a[mt][kk] = ld8((const unsigned short*)((char*)Ash[b] +
                                (w * 16 + mt * 64 + c) * 128 + (((kk * 4 + qd) ^ cs) << 4)));
#pragma unroll
        for (int nb = 0; nb < 4; ++nb)
#pragma unroll
            for (int kk = 0; kk < 2; ++kk)
                bq[nb][kk] = ld8((const unsigned short*)((char*)Bsh[b] +
                                (nb * 16 + c) * 128 + (((kk * 4 + qd) ^ cs) << 4)));
        asm volatile("s_waitcnt lgkmcnt(0)" ::: "memory");
        __syncthreads();
#pragma unroll
        for (int kk = 0; kk < 2; ++kk)
#pragma unroll
            for (int nb = 0; nb < 4; ++nb) {
                acc[0][nb] = __builtin_amdgcn_mfma_f32_16x16x32_bf16(a[0][kk], bq[nb][kk], acc[0][nb], 0, 0, 0);
                acc[1][nb] = __builtin_amdgcn_mfma_f32_16x16x32_bf16(a[1][kk], bq[nb][kk], acc[1][nb], 0, 0, 0);
            }
    }

    if (z == 2) {
        // V: write transposed [bh][d][i], 4 consecutive i packed per store
#pragma unroll
        for (int mt = 0; mt < 2; ++mt) {
            int ib = m0 + mt * 64 + qd * 4;      // i base (4-aligned)
            int b = ib >> 11, i = ib & 2047;
#pragma unroll
            for (int nb = 0; nb < 4; ++nb) {
                int col = n0 + nb * 16 + c;      // h*64 + d
                int h = col >> 6, d = col & 63;
                ushort4 pk;
                pk.x = f2bf(acc[mt][nb][0]); pk.y = f2bf(acc[mt][nb][1]);
                pk.z = f2bf(acc[mt][nb][2]); pk.w = f2bf(acc[mt][nb][3]);
                *(ushort4*)(vt + (((b << 3) + h) * 64 + d) * 2048 + i) = pk;
            }
        }
    } else {
        float scale = (z == 0) ? QSCALE : 1.0f;
#pragma unroll
        for (int mt = 0; mt < 2; ++mt)
#pragma unroll
            for (int nb = 0; nb < 4; ++nb) {
#pragma unroll
                for (int r = 0; r < 4; ++r) {
                    int row = m0 + mt * 64 + qd * 4 + r;
                    int col = n0 + nb * 16 + c;
                    int b = row >> 11, i = row & 2047, h = col >> 6, d = col & 63;
                    out[(((b << 3) + h) * 2048 + i) * 64 + d] = f2bf(acc[mt][nb][r] * scale);
                }
            }
    }
}

// ------------- Flash attention v10 (R9 body) + Wo-prep rider blocks (R11-verified) ---
// grid 1088: blocks 0..63 transpose-cast Wo -> woT; blocks 64..1087 flash.
__global__ __launch_bounds__(256, 4)
void ca_flash(const unsigned short* __restrict__ Q,
              const unsigned short* __restrict__ K,
              const unsigned short* __restrict__ VT,
              const float* __restrict__ rel_pos,
              const float* __restrict__ c_emb,
              unsigned short* __restrict__ Ob,
              const float* __restrict__ Wo,
              unsigned short* __restrict__ woT) {
    __shared__ __align__(16) char smem[37904];

    if (blockIdx.x < 64) {
        // ---- Wo transpose-cast rider ----
        float (*T)[65] = (float (*)[65])smem;     // 16.6KB < 37.9KB
        int t = blockIdx.x;
        int k0 = (t & 7) << 6, n0 = (t >> 3) << 6;
        int c = threadIdx.x & 63, r4 = threadIdx.x >> 6;
#pragma unroll
        for (int rr = 0; rr < 16; ++rr) {
            int r = r4 * 16 + rr;
            T[r][c] = Wo[(k0 + r) * 512 + n0 + c];
        }
        __syncthreads();
#pragma unroll
        for (int rr = 0; rr < 16; ++rr) {
            int r = r4 * 16 + rr;
            woT[(n0 + r) * 512 + k0 + c] = f2bf(T[c][r]);
        }
        return;
    }

    unsigned (*Ptu)[16][16] = (unsigned (*)[16][16])(smem + 32768);
    float* red = (float*)smem;                       // [3][64][41] floats
    float2* lrg = (float2*)(smem + 36864);           // (rel*QSCALE, gate) x 129

    int bx = blockIdx.x - 64;
    int xcd = bx & 7, slot = bx >> 3;           // slot 0..127
    int bh = xcd + ((slot >> 6) << 3);          // heads {xcd, xcd+8} per XCD
    int it = slot & 63;
    int b = bh >> 3, h = bh & 7;
    int w = threadIdx.x >> 6, lane = threadIdx.x & 63;
    int c = lane & 15, qd = lane >> 4;
    int i0 = it * 32;

    if (threadIdx.x < 129) {
        lrg[threadIdx.x] = make_float2(rel_pos[threadIdx.x * 8 + h] * QSCALE,
                                       c_emb[threadIdx.x * 8 + h]);
    }

    const unsigned short* Qh = Q  + bh * 131072;
    const unsigned short* Kh = K  + bh * 131072;
    const unsigned short* Vh = VT + bh * 131072;
    char* kw = smem + w * 4096;                 // wave-private K slab (32 rows x 128B)
    char* vw = smem + 16384 + w * 4096;         // wave-private V slab (64 rows x 64B)

    int koff[4], voff[4];
#pragma unroll
    for (int L = 0; L < 4; ++L) {
        int kr = L * 8 + (lane >> 3);
        koff[L] = kr * 64 + (((lane & 7) ^ ((kr >> 1) & 7)) << 3);
        int vr = L * 16 + (lane >> 2);
        voff[L] = vr * 2048 + (((lane & 3) ^ ((lane >> 3) & 3)) << 3);
    }

    // prologue: stage tile t=0 (j0 = w*32): K first, then V (vmcnt(4) split)
    {
        int j0 = w * 32;
#pragma unroll
        for (int L = 0; L < 4; ++L) gld_lds16(Kh + j0 * 64 + koff[L], kw + L * 1024);
#pragma unroll
        for (int L = 0; L < 4; ++L) gld_lds16(Vh + j0 + voff[L], vw + L * 1024);
    }

    bf16x8 aq[2][2];
#pragma unroll
    for (int qt = 0; qt < 2; ++qt) {
        aq[qt][0] = ld8(Qh + (i0 + qt * 16 + c) * 64 + qd * 8);
        aq[qt][1] = ld8(Qh + (i0 + qt * 16 + c) * 64 + 32 + qd * 8);
    }

    f32x4 o2[2][4];
    float lp2[2][4];
#pragma unroll
    for (int qt = 0; qt < 2; ++qt)
#pragma unroll
        for (int db = 0; db < 4; ++db) {
            o2[qt][db] = (f32x4){0.f, 0.f, 0.f, 0.f};
            lp2[qt][db] = 0.f;
        }

    __syncthreads();   // lrg ready (also drains prologue stage - harmless)

    int ksw  = c & 7;          // (row>>1)&7 for K rows 2c, 2c+1
    int vsw  = (c >> 1) & 3;   // (row>>1)&3 for V rows db*16+c

    for (int t = 0; t < 16; ++t) {
        asm volatile("s_waitcnt vmcnt(4)" ::: "memory");
        __builtin_amdgcn_sched_barrier(0);
        bf16x8 bk0a = ld8((const unsigned short*)(kw + (2 * c) * 128     + (((qd)     ^ ksw) << 4)));
        bf16x8 bk0b = ld8((const unsigned short*)(kw + (2 * c) * 128     + (((qd + 4) ^ ksw) << 4)));
        bf16x8 bk1a = ld8((const unsigned short*)(kw + (2 * c + 1) * 128 + (((qd)     ^ ksw) << 4)));
        bf16x8 bk1b = ld8((const unsigned short*)(kw + (2 * c + 1) * 128 + (((qd + 4) ^ ksw) << 4)));
        asm volatile("s_waitcnt vmcnt(0)" ::: "memory");
        __builtin_amdgcn_sched_barrier(0);
        bf16x8 bv[4];
#pragma unroll
        for (int db = 0; db < 4; ++db)
            bv[db] = ld8((const unsigned short*)(vw + (db * 16 + c) * 64 + ((qd ^ vsw) << 4)));
        asm volatile("s_waitcnt lgkmcnt(0)" ::: "memory");
        __builtin_amdgcn_sched_barrier(0);
        if (t < 15) {
            int j0n = ((t + 1) * 4 + w) * 32;
#pragma unroll
            for (int L = 0; L < 4; ++L) gld_lds16(Kh + j0n * 64 + koff[L], kw + L * 1024);
#pragma unroll
            for (int L = 0; L < 4; ++L) gld_lds16(Vh + j0n + voff[L], vw + L * 1024);
        }

        int j0 = (t * 4 + w) * 32;

        // ---- hoisted QK: all 4 accumulators before any softmax ----
        f32x4 s[2][2];
        __builtin_amdgcn_s_setprio(1);
#pragma unroll
        for (int qt = 0; qt < 2; ++qt) {
            s[qt][0] = (f32x4){0.f, 0.f, 0.f, 0.f};
            s[qt][1] = (f32x4){0.f, 0.f, 0.f, 0.f};
            s[qt][0] = __builtin_amdgcn_mfma_f32_16x16x32_bf16(aq[qt][0], bk0a, s[qt][0], 0, 0, 0);
            s[qt][1] = __builtin_amdgcn_mfma_f32_16x16x32_bf16(aq[qt][0], bk1a, s[qt][1], 0, 0, 0);
            s[qt][0] = __builtin_amdgcn_mfma_f32_16x16x32_bf16(aq[qt][1], bk0b, s[qt][0], 0, 0, 0);
            s[qt][1] = __builtin_amdgcn_mfma_f32_16x16x32_bf16(aq[qt][1], bk1b, s[qt][1], 0, 0, 0);
        }
        __builtin_amdgcn_s_setprio(0);

#pragma unroll
        for (int qt = 0; qt < 2; ++qt) {
            int iqt0 = i0 + qt * 16;
            int iq = iqt0 + qd * 4;
            bool lowc  = (j0 + 31 - iqt0) <= -64;   // whole tile clamps to d=0
            bool highc = (j0 - (iqt0 + 15)) >= 64;  // whole tile clamps to d=128
            if (lowc || highc) {
                int d = lowc ? 0 : 128;
                float2 gg = lrg[d];                 // wave-uniform broadcast
#pragma unroll
                for (int r = 0; r < 4; ++r) {
                    float t0 = EXP2(s[qt][0][r] + gg.x);
                    float t1 = EXP2(s[qt][1][r] + gg.x);
                    lp2[qt][r] += t0 + t1;
                    Ptu[w][qd * 4 + r][c] = pk2(t0 * gg.y, t1 * gg.y);
                }
            } else {
#pragma unroll
                for (int r = 0; r < 4; ++r) {
                    int i = iq + r;
                    int j = j0 + 2 * c;
                    int d0 = j - i;     d0 = (d0 < -64) ? -64 : (d0 > 64 ? 64 : d0); d0 += 64;
                    int d1 = j + 1 - i; d1 = (d1 < -64) ? -64 : (d1 > 64 ? 64 : d1); d1 += 64;
                    float2 g0 = lrg[d0];
                    float2 g1 = lrg[d1];
                    float t0 = EXP2(s[qt][0][r] + g0.x);
                    float t1 = EXP2(s[qt][1][r] + g1.x);
                    lp2[qt][r] += t0 + t1;
                    Ptu[w][qd * 4 + r][c] = pk2(t0 * g0.y, t1 * g1.y);
                }
            }
            // same-wave RAW on Ptu: lgkmcnt ordering, no barrier needed
            bf16x8 ap = ld8((const unsigned short*)&Ptu[w][c][0] + qd * 8);
            __builtin_amdgcn_s_setprio(1);
#pragma unroll
            for (int db = 0; db < 4; ++db)
                o2[qt][db] = __builtin_amdgcn_mfma_f32_16x16x32_bf16(ap, bv[db], o2[qt][db], 0, 0, 0);
            __builtin_amdgcn_s_setprio(0);
        }
    }

    // ---- cross-wave combine (red overlaps staging slabs: barrier before reuse;
    //      last iter issued no prefetch, so no async LDS writes are in flight) ----
    __syncthreads();
    if (w > 0) {
        float* dst = red + (w - 1) * (64 * 41) + lane * 41;
#pragma unroll
        for (int qt = 0; qt < 2; ++qt)
#pragma unroll
            for (int db = 0; db < 4; ++db)
#pragma unroll
                for (int r = 0; r < 4; ++r)
                    dst[qt * 16 + db * 4 + r] = o2[qt][db][r];
#pragma unroll
        for (int qt = 0; qt < 2; ++qt)
#pragma unroll
            for (int r = 0; r < 4; ++r)
                dst[32 + qt * 4 + r] = lp2[qt][r];
    }
    __syncthreads();
    if (w == 0) {
#pragma unroll
        for (int ww = 0; ww < 3; ++ww) {
            const float* src = red + ww * (64 * 41) + lane * 41;
#pragma unroll
            for (int qt = 0; qt < 2; ++qt) {
#pragma unroll
                for (int db = 0; db < 4; ++db)
#pragma unroll
                    for (int r = 0; r < 4; ++r)
                        o2[qt][db][r] += src[qt * 16 + db * 4 + r];
#pragma unroll
                for (int r = 0; r < 4; ++r)
                    lp2[qt][r] += src[32 + qt * 4 + r];
            }
        }
#pragma unroll
        for (int qt = 0; qt < 2; ++qt)
#pragma unroll
            for (int r = 0; r < 4; ++r) {
                lp2[qt][r] += __shfl_xor(lp2[qt][r], 1);
                lp2[qt][r] += __shfl_xor(lp2[qt][r], 2);
                lp2[qt][r] += __shfl_xor(lp2[qt][r], 4);
                lp2[qt][r] += __shfl_xor(lp2[qt][r], 8);
            }
#pragma unroll
        for (int qt = 0; qt < 2; ++qt)
#pragma unroll
            for (int db = 0; db < 4; ++db)
#pragma unroll
                for (int r = 0; r < 4; ++r) {
                    int row = b * 2048 + i0 + qt * 16 + qd * 4 + r;
                    int col = h * 64 + db * 16 + c;
                    Ob[row * 512 + col] = f2bf(o2[qt][db][r] / lp2[qt][r]);
                }
    }
}

// ------------- Output GEMM v3 (R9-proven): dbuf staging, counted vmcnt, grid (64,8) --
__global__ __launch_bounds__(256, 4)
void ca_gemm_out(const unsigned short* __restrict__ A,
                 const unsigned short* __restrict__ BT,
                 const float* __restrict__ bias,
                 float* __restrict__ out) {
    __shared__ __align__(16) unsigned short Ash[2][64 * 64];
    __shared__ __align__(16) unsigned short Bsh[2][64 * 64];
    int w = threadIdx.x >> 6, lane = threadIdx.x & 63;
    int c = lane & 15, qd = lane >> 4;
    int m0 = blockIdx.x * 64 + w * 16;
    int n0 = blockIdx.y * 64;

    int lr = lane >> 3, ls = lane & 7;
    int soff = lr * 512 + ((ls ^ (lr & 7)) << 3);
    const unsigned short* Ab = A + (blockIdx.x * 64) * 512 + soff;
    const unsigned short* Bb = BT + n0 * 512 + soff;

#pragma unroll
    for (int L = 0; L < 2; ++L) {
        gld_lds16(Ab + (w * 16 + L * 8) * 512, (char*)Ash[0] + (w * 16 + L * 8) * 128);
        gld_lds16(Bb + (w * 16 + L * 8) * 512, (char*)Bsh[0] + (w * 16 + L * 8) * 128);
    }

    f32x4 acc[4];
#pragma unroll
    for (int nb = 0; nb < 4; ++nb) acc[nb] = (f32x4){0.f, 0.f, 0.f, 0.f};

    int cs = c & 7;
#pragma unroll
    for (int k = 0; k < 8; ++k) {
        int b = k & 1;
        if (k < 7) {
            int k0 = (k + 1) * 64;
#pragma unroll
            for (int L = 0; L < 2; ++L) {
                gld_lds16(Ab + k0 + (w * 16 + L * 8) * 512, (char*)Ash[b ^ 1] + (w * 16 + L * 8) * 128);
                gld_lds16(Bb + k0 + (w * 16 + L * 8) * 512, (char*)Bsh[b ^ 1] + (w * 16 + L * 8) * 128);
            }
            asm volatile("s_waitcnt vmcnt(4)" ::: "memory");
        } else {
            asm volatile("s_waitcnt vmcnt(0)" ::: "memory");
        }
        __syncthreads();
        bf16x8 a[2], bq[4][2];
#pragma unroll
        for (int kk = 0; kk < 2; ++kk)
            a[kk] = ld8((const unsigned short*)((char*)Ash[b] +
                        (w * 16 + c) * 128 + (((kk * 4 + qd) ^ cs) << 4)));
#pragma unroll
        for (int nb = 0; nb < 4; ++nb)
#pragma unroll
            for (int kk = 0; kk < 2; ++kk)
                bq[nb][kk] = ld8((const unsigned short*)((char*)Bsh[b] +
                                (nb * 16 + c) * 128 + (((kk * 4 + qd) ^ cs) << 4)));
        asm volatile("s_waitcnt lgkmcnt(0)" ::: "memory");
        __syncthreads();
#pragma unroll
        for (int kk = 0; kk < 2; ++kk)
#pragma unroll
            for (int nb = 0; nb < 4; ++nb)
                acc[nb] = __builtin_amdgcn_mfma_f32_16x16x32_bf16(a[kk], bq[nb][kk], acc[nb], 0, 0, 0);
    }
#pragma unroll
    for (int nb = 0; nb < 4; ++nb) {
#pragma unroll
        for (int r = 0; r < 4; ++r) {
            int row = m0 + qd * 4 + r;
            int col = n0 + nb * 16 + c;
            out[row * 512 + col] = acc[nb][r] + bias[col];
        }
    }
}

extern "C" void kernel_launch(void* const* d_in, const int* in_sizes, int n_in,
                              void* d_out, int out_size, void* d_ws, size_t ws_size,
                              hipStream_t stream) {
    const float* x   = (const float*)d_in[0];
    const float* Wq  = (const float*)d_in[1];
    const float* Wk  = (const float*)d_in[2];
    const float* Wv  = (const float*)d_in[3];
    const float* rel = (const float*)d_in[4];
    const float* cem = (const float*)d_in[5];
    const float* Wo  = (const float*)d_in[6];
    const float* bo  = (const float*)d_in[7];
    float* out = (float*)d_out;
    char* ws = (char*)d_ws;

    unsigned short* xb  = (unsigned short*)(ws);              // 4 MB
    unsigned short* wts = (unsigned short*)(ws + 4194304);    // 1.5 MB (Wq,Wk,Wv ^T)
    unsigned short* woT = (unsigned short*)(ws + 5767168);    // 512 KB Wo^T
    unsigned short* qkv = (unsigned short*)(ws + 6291456);    // q,k
    unsigned short* vt  = (unsigned short*)(ws + 18874368);   // 4 MB  vT bf16 [bh][DH][N]
    unsigned short* ob  = (unsigned short*)(ws + 23068672);   // 4 MB

    hipLaunchKernelGGL(ca_prep, dim3(1216), dim3(256), 0, stream, x, Wq, Wk, Wv, xb, wts);
    hipLaunchKernelGGL(ca_gemm_proj, dim3(32, 24), dim3(256), 0, stream, xb, wts, qkv, vt);
    hipLaunchKernelGGL(ca_flash, dim3(1088), dim3(256), 0, stream,
                       qkv, qkv + 2097152, vt, rel, cem, ob, Wo, woT);
    hipLaunchKernelGGL(ca_gemm_out, dim3(64, 8), dim3(256), 0, stream, ob, woT, bo, out);
}